// Round 7
// baseline (13681.065 us; speedup 1.0000x reference)
//
#include <hip/hip_runtime.h>
#include <hip/hip_fp16.h>
#include <math.h>

#define L_SEQ 4096
#define H_DIM 512
#define M_DIM 1024
#define G4    2048   // 4*H
#define N_WG  32
#define CHUNK 16     // h indices per workgroup
#define POLL_CAP (1 << 16)  // watchdog: finite wrong run instead of hang

#define OUT_HT 0
#define OUT_CT 512
#define OUT_Y  1024
#define OUT_A  (1024 + L_SEQ*H_DIM)   // 2098176

typedef unsigned long long ull;

__device__ __forceinline__ float fast_sigmoid(float v) {
    return 1.0f / (1.0f + __expf(-v));
}
__device__ __forceinline__ float fast_tanh(float v) {
    const float ax = fabsf(v);
    const float e = __expf(2.0f * ax);          // inf for large ax -> r = 1
    const float r = 1.0f - 2.0f / (e + 1.0f);
    return copysignf(r, v);
}

// Opaque 16B load: the asm result cannot be rematerialized, so the value MUST
// stay register-resident across the whole time loop (the compiler was sinking
// ordinary invariant loads back into the loop -> 128 KB/CU/step L2 streaming).
__device__ __forceinline__ float4 ld_f4_pin(const float* p) {
    float4 r;
    asm volatile("global_load_dwordx4 %0, %1, off\n\ts_waitcnt vmcnt(0)"
                 : "=v"(r) : "v"(p));
    return r;
}

__device__ __forceinline__ ull ld_word(ull* p) {
    return __hip_atomic_load(p, __ATOMIC_RELAXED, __HIP_MEMORY_SCOPE_AGENT);
}

// ---------------------------------------------------------------------------
// x[l, :] = embed[sent[l], :]
// ---------------------------------------------------------------------------
__global__ void gather_embed(const int* __restrict__ sent,
                             const float* __restrict__ embed,
                             float* __restrict__ x) {
    const int l = blockIdx.x;
    const int t = threadIdx.x;          // 128 threads, float4 each
    const int row = sent[l];
    const float4 v = *(const float4*)&embed[(size_t)row * H_DIM + t * 4];
    *(float4*)&x[(size_t)l * H_DIM + t * 4] = v;
}

// ---------------------------------------------------------------------------
// Generic fp32 tile GEMM (64x64 tile, BK=16, 256 thr, 4x4 micro) — unchanged.
// ---------------------------------------------------------------------------
template<bool AT, bool BT, bool ADD_C, bool BIAS>
__global__ __launch_bounds__(256) void gemm_tile(
    const float* __restrict__ A, int lda,
    const float* __restrict__ B, int ldb,
    float* __restrict__ C, int ldc,
    int K,
    const float* __restrict__ bias1,
    const float* __restrict__ bias2) {

    __shared__ float sA[16][68];
    __shared__ float sB[16][68];

    const int tid = threadIdx.x;
    const int i0 = blockIdx.y * 64;
    const int j0 = blockIdx.x * 64;
    const int ti = tid & 15;
    const int tj = tid >> 4;

    float acc[4][4] = {};

    for (int k0 = 0; k0 < K; k0 += 16) {
        if (!AT) {
            const int row = tid >> 2, kq = tid & 3;
            const float4 v = *(const float4*)&A[(size_t)(i0 + row) * lda + k0 + kq * 4];
            sA[kq * 4 + 0][row] = v.x;
            sA[kq * 4 + 1][row] = v.y;
            sA[kq * 4 + 2][row] = v.z;
            sA[kq * 4 + 3][row] = v.w;
        } else {
            const int krow = tid >> 4, ic = tid & 15;
            const float4 v = *(const float4*)&A[(size_t)(k0 + krow) * lda + i0 + ic * 4];
            *(float4*)&sA[krow][ic * 4] = v;
        }
        if (BT) {
            const int row = tid >> 2, kq = tid & 3;
            const float4 v = *(const float4*)&B[(size_t)(j0 + row) * ldb + k0 + kq * 4];
            sB[kq * 4 + 0][row] = v.x;
            sB[kq * 4 + 1][row] = v.y;
            sB[kq * 4 + 2][row] = v.z;
            sB[kq * 4 + 3][row] = v.w;
        } else {
            const int krow = tid >> 4, jc = tid & 15;
            const float4 v = *(const float4*)&B[(size_t)(k0 + krow) * ldb + j0 + jc * 4];
            *(float4*)&sB[krow][jc * 4] = v;
        }
        __syncthreads();

        #pragma unroll
        for (int kk = 0; kk < 16; ++kk) {
            const float4 a4 = *(const float4*)&sA[kk][ti * 4];
            const float4 b4 = *(const float4*)&sB[kk][tj * 4];
            const float av[4] = {a4.x, a4.y, a4.z, a4.w};
            const float bv[4] = {b4.x, b4.y, b4.z, b4.w};
            #pragma unroll
            for (int ii = 0; ii < 4; ++ii)
                #pragma unroll
                for (int jjx = 0; jjx < 4; ++jjx)
                    acc[ii][jjx] = fmaf(av[ii], bv[jjx], acc[ii][jjx]);
        }
        __syncthreads();
    }

    #pragma unroll
    for (int ii = 0; ii < 4; ++ii) {
        const size_t crow = (size_t)(i0 + ti * 4 + ii) * ldc + j0 + tj * 4;
        #pragma unroll
        for (int jjx = 0; jjx < 4; ++jjx) {
            float v = acc[ii][jjx];
            if constexpr (BIAS) {
                const int col = j0 + tj * 4 + jjx;
                v += bias1[col] + bias2[col];
            }
            if constexpr (ADD_C) v += C[crow + jjx];
            C[crow + jjx] = v;
        }
    }
}

// ---------------------------------------------------------------------------
// Row softmax of T [M_DIM x L_SEQ], in place. One block per row. Unchanged.
// ---------------------------------------------------------------------------
__global__ __launch_bounds__(256) void softmax_rows(float* __restrict__ T) {
    __shared__ float red[8];
    const int m = blockIdx.x;
    const int tid = threadIdx.x;
    float* row = T + (size_t)m * L_SEQ;

    float4 v[4];
    #pragma unroll
    for (int c = 0; c < 4; ++c)
        v[c] = *(const float4*)&row[c * 1024 + tid * 4];

    float mx = -INFINITY;
    #pragma unroll
    for (int c = 0; c < 4; ++c)
        mx = fmaxf(mx, fmaxf(fmaxf(v[c].x, v[c].y), fmaxf(v[c].z, v[c].w)));
    #pragma unroll
    for (int o = 32; o; o >>= 1) mx = fmaxf(mx, __shfl_xor(mx, o));
    if ((tid & 63) == 0) red[tid >> 6] = mx;
    __syncthreads();
    mx = fmaxf(fmaxf(red[0], red[1]), fmaxf(red[2], red[3]));

    float sum = 0.0f;
    #pragma unroll
    for (int c = 0; c < 4; ++c) {
        v[c].x = expf(v[c].x - mx);
        v[c].y = expf(v[c].y - mx);
        v[c].z = expf(v[c].z - mx);
        v[c].w = expf(v[c].w - mx);
        sum += (v[c].x + v[c].y) + (v[c].z + v[c].w);
    }
    #pragma unroll
    for (int o = 32; o; o >>= 1) sum += __shfl_xor(sum, o);
    if ((tid & 63) == 0) red[4 + (tid >> 6)] = sum;
    __syncthreads();
    sum = (red[4] + red[5]) + (red[6] + red[7]);
    const float inv = 1.0f / sum;

    #pragma unroll
    for (int c = 0; c < 4; ++c) {
        v[c].x *= inv; v[c].y *= inv; v[c].z *= inv; v[c].w *= inv;
        *(float4*)&row[c * 1024 + tid * 4] = v[c];
    }
}

__global__ void copyA(const float* __restrict__ A, float* __restrict__ dst) {
    const int idx = blockIdx.x * 256 + threadIdx.x;
    ((float4*)dst)[idx] = ((const float4*)A)[idx];
}

// ---------------------------------------------------------------------------
// Persistent multi-workgroup LSTM, fp16-pair stamped broadcast (R0 protocol,
// R0 PACKED layout — R6 proved line-padding only adds fetch, no latency win)
// + pinned-in-VGPR weights. 32 WGs x 256 threads. WG b owns h indices
// [b*16, b*16+16).
//   jj = wave*4 + ((lane>>4)&3) : local h index;  kg = lane&15 : k-slice.
// Broadcast: hbuf[t&1][256] u64 words; word j = stamp(t+1)<<32 |
// fp16(h[2j+1])<<16 | fp16(h[2j]). One relaxed agent-scope atomic store per
// word. 2-deep hbuf overwrite-safe: reaching t+2 requires having observed
// all of t+1 (barrier-gated).
//
// R7 theory: step time = serial latency chain (compute -> store visible at
// coherence point -> reader DISCOVERY by sampling -> barrier on slowest of
// 256 discoveries). R6 showed poll *traffic* doesn't matter; sampling period
// does. k loads in flight sample every RT/k — bump k to 4 (uniform on every
// thread; R4 proved role-split poll loops serialize under the exec mask).
// out[] stores after the poll (retirement rides under next step's compute).
// POLL_CAP watchdog (R4-proven): finite wrong run instead of a hung
// container; never fires healthy.
// ---------------------------------------------------------------------------
__global__ __launch_bounds__(256, 1) void lstm_kernel(
    const float* __restrict__ Gm,     // [L_SEQ, G4] x-part + biases
    const float* __restrict__ W_hh,   // [G4, H_DIM]
    const float* __restrict__ h0,
    const float* __restrict__ c0,
    float* __restrict__ out,
    ull* hbuf) {                      // [2][256] stamped fp16-pair words

    __shared__ __align__(16) float sH[2][H_DIM];

    const int tid  = threadIdx.x;
    const int b    = blockIdx.x;
    const int lane = tid & 63;
    const int wave = tid >> 6;
    const int m    = (lane >> 4) & 3;
    const int jj   = wave * 4 + m;
    const int kg   = lane & 15;
    const int gj   = b * CHUNK + jj;          // global h index this thread serves

    // --- weights, rotated by kg, PINNED in VGPRs via opaque asm loads
    float4 w[4][8];
    #pragma unroll
    for (int g = 0; g < 4; ++g) {
        const float* wrow = W_hh + (size_t)(g * H_DIM + gj) * H_DIM + kg * 32;
        #pragma unroll
        for (int i = 0; i < 8; ++i)
            w[g][i] = ld_f4_pin(&wrow[((i + kg) & 7) * 4]);
    }

    // --- init h, c
    {
        const int i2 = tid * 2;
        sH[0][i2]     = h0[i2];
        sH[0][i2 + 1] = h0[i2 + 1];
    }
    float c = 0.0f;
    if (kg == 0) c = c0[gj];
    __syncthreads();

    // --- prefetch gate inputs for t=0
    float gin0 = 0.f, gin1 = 0.f, gin2 = 0.f, gin3 = 0.f;
    if (kg == 0) {
        const float* gp = Gm + gj;
        gin0 = gp[0 * H_DIM];
        gin1 = gp[1 * H_DIM];
        gin2 = gp[2 * H_DIM];
        gin3 = gp[3 * H_DIM];
    }

    bool dead = false;   // sticky watchdog flag — never set in a healthy run

    for (int t = 0; t < L_SEQ; ++t) {
        const float4* sH4 = (const float4*)sH[t & 1];

        // prefetch gate inputs for t+1 (latency hides under this whole step)
        float nin0 = 0.f, nin1 = 0.f, nin2 = 0.f, nin3 = 0.f;
        if (kg == 0 && t + 1 < L_SEQ) {
            const float* gp = Gm + (size_t)(t + 1) * G4 + gj;
            nin0 = gp[0 * H_DIM];
            nin1 = gp[1 * H_DIM];
            nin2 = gp[2 * H_DIM];
            nin3 = gp[3 * H_DIM];
        }

        // partial dots: 4 gates x 32 k-floats
        float4 a0 = {0, 0, 0, 0}, a1 = {0, 0, 0, 0}, a2 = {0, 0, 0, 0}, a3 = {0, 0, 0, 0};
        #pragma unroll
        for (int i = 0; i < 8; ++i) {
            const float4 hv = sH4[kg * 8 + ((i + kg) & 7)];
            a0.x = fmaf(w[0][i].x, hv.x, a0.x); a0.y = fmaf(w[0][i].y, hv.y, a0.y);
            a0.z = fmaf(w[0][i].z, hv.z, a0.z); a0.w = fmaf(w[0][i].w, hv.w, a0.w);
            a1.x = fmaf(w[1][i].x, hv.x, a1.x); a1.y = fmaf(w[1][i].y, hv.y, a1.y);
            a1.z = fmaf(w[1][i].z, hv.z, a1.z); a1.w = fmaf(w[1][i].w, hv.w, a1.w);
            a2.x = fmaf(w[2][i].x, hv.x, a2.x); a2.y = fmaf(w[2][i].y, hv.y, a2.y);
            a2.z = fmaf(w[2][i].z, hv.z, a2.z); a2.w = fmaf(w[2][i].w, hv.w, a2.w);
            a3.x = fmaf(w[3][i].x, hv.x, a3.x); a3.y = fmaf(w[3][i].y, hv.y, a3.y);
            a3.z = fmaf(w[3][i].z, hv.z, a3.z); a3.w = fmaf(w[3][i].w, hv.w, a3.w);
        }
        float s0 = (a0.x + a0.y) + (a0.z + a0.w);
        float s1 = (a1.x + a1.y) + (a1.z + a1.w);
        float s2 = (a2.x + a2.y) + (a2.z + a2.w);
        float s3 = (a3.x + a3.y) + (a3.z + a3.w);
        #pragma unroll
        for (int msk = 1; msk <= 8; msk <<= 1) {
            s0 += __shfl_xor(s0, msk);
            s1 += __shfl_xor(s1, msk);
            s2 += __shfl_xor(s2, msk);
            s3 += __shfl_xor(s3, msk);
        }

        float h = 0.0f;
        if (kg == 0) {
            const float i_ = fast_sigmoid(s0 + gin0);
            const float f_ = fast_sigmoid(s1 + gin1);
            const float g_ = fast_tanh(s2 + gin2);
            const float o_ = fast_sigmoid(s3 + gin3);
            c = f_ * c + i_ * g_;
            h = o_ * fast_tanh(c);
            // pair up: even-jj lane gets odd-jj partner's h (lane 0<-16, 32<-48)
            const float hp = __shfl_xor(h, 16);
            if ((m & 1) == 0) {
                const __half2 p2 = __floats2half2_rn(h, hp);   // lo = even jj
                const unsigned bits = __builtin_bit_cast(unsigned, p2);
                const ull pack = ((ull)(unsigned)(t + 1) << 32) | (ull)bits;
                __hip_atomic_store(&hbuf[(t & 1) * 256 + (gj >> 1)], pack,
                                   __ATOMIC_RELAXED, __HIP_MEMORY_SCOPE_AGENT);
            }
        }
        gin0 = nin0; gin1 = nin1; gin2 = nin2; gin3 = nin3;

        if (t + 1 < L_SEQ) {
            // UNIFORM poll on every thread (word tid), FOUR loads in flight:
            // sampling period ~ RT/4, and the end-of-step barrier waits on
            // the max over 256 discoveries — k=4 trims that tail.
            const unsigned want = (unsigned)(t + 1);
            ull* src = &hbuf[(t & 1) * 256 + tid];
            ull va = ld_word(src);
            ull vb = ld_word(src);
            ull vc = ld_word(src);
            ull vd = ld_word(src);
            ull v = va;
            int guard = 0;
            for (;;) {
                if ((unsigned)(va >> 32) == want) { v = va; break; }
                if ((unsigned)(vb >> 32) == want) { v = vb; break; }
                if ((unsigned)(vc >> 32) == want) { v = vc; break; }
                if ((unsigned)(vd >> 32) == want) { v = vd; break; }
                if (dead) { v = va; break; }
                if (++guard > POLL_CAP) { dead = true; v = va; break; }
                va = ld_word(src);
                vb = ld_word(src);
                vc = ld_word(src);
                vd = ld_word(src);
            }
            const float2 f2 = __half22float2(__builtin_bit_cast(__half2, (unsigned)v));
            float* dstp = sH[(t + 1) & 1];
            dstp[tid * 2]     = f2.x;
            dstp[tid * 2 + 1] = f2.y;
        }

        // out[] stores AFTER the poll: their retirement rides under the next
        // step's compute instead of serializing into this step's poll waits.
        if (kg == 0) {
            out[OUT_Y + (size_t)t * H_DIM + gj] = h;
            if (t == L_SEQ - 1) {
                out[OUT_HT + gj] = h;
                out[OUT_CT + gj] = c;
                out[OUT_A + (size_t)M_DIM * H_DIM + gj] = h;   // A_new last row
            }
        }
        __syncthreads();
    }
}

// ---------------------------------------------------------------------------
extern "C" void kernel_launch(void* const* d_in, const int* in_sizes, int n_in,
                              void* d_out, int out_size, void* d_ws, size_t ws_size,
                              hipStream_t stream) {
    const int*   sent  = (const int*)d_in[0];
    const float* h0    = (const float*)d_in[1];
    const float* c0    = (const float*)d_in[2];
    const float* A     = (const float*)d_in[3];
    const float* embed = (const float*)d_in[4];
    const float* W_ih  = (const float*)d_in[5];
    const float* W_hh  = (const float*)d_in[6];
    const float* b_ih  = (const float*)d_in[7];
    const float* b_hh  = (const float*)d_in[8];
    float* out = (float*)d_out;

    float* ws = (float*)d_ws;
    float* x    = ws;                                  // L*H       (8 MB)
    float* T    = x + (size_t)L_SEQ * H_DIM;           // M*L       (16 MB)
    float* Gm   = T + (size_t)M_DIM * L_SEQ;           // L*4H      (32 MB)
    ull*   hbuf = (ull*)(Gm + (size_t)L_SEQ * G4);     // 2*256 u64 (R0 layout)
    // 0xAA poison in hbuf: stamp 0xAAAAAAAA never equals a wanted stamp.

    // x = embed[sent]
    gather_embed<<<L_SEQ, 128, 0, stream>>>(sent, embed, x);

    // T = A @ x^T   [M, L], K = H
    gemm_tile<false, true, false, false><<<dim3(L_SEQ / 64, M_DIM / 64), 256, 0, stream>>>(
        A, H_DIM, x, H_DIM, T, L_SEQ, H_DIM, nullptr, nullptr);

    // row softmax over L
    softmax_rows<<<M_DIM, 256, 0, stream>>>(T);

    // x += T^T @ A   [L, H], K = M
    gemm_tile<true, false, true, false><<<dim3(H_DIM / 64, L_SEQ / 64), 256, 0, stream>>>(
        T, L_SEQ, A, H_DIM, x, H_DIM, M_DIM, nullptr, nullptr);

    // G = x @ W_ih^T + b_ih + b_hh   [L, 4H], K = H
    gemm_tile<false, true, false, true><<<dim3(G4 / 64, L_SEQ / 64), 256, 0, stream>>>(
        x, H_DIM, W_ih, H_DIM, Gm, G4, H_DIM, b_ih, b_hh);

    // A_new rows 0..M-1
    copyA<<<(M_DIM * H_DIM / 4) / 256, 256, 0, stream>>>(A, out + OUT_A);

    // sequential LSTM over L steps (fp16-pair stamped broadcast, pinned weights)
    lstm_kernel<<<N_WG, 256, 0, stream>>>(Gm, W_hh, h0, c0, out, hbuf);
}

// Round 8
// 8207.822 us; speedup vs baseline: 1.6668x; 1.6668x over previous
//
#include <hip/hip_runtime.h>
#include <hip/hip_fp16.h>
#include <math.h>

#define L_SEQ 4096
#define H_DIM 512
#define M_DIM 1024
#define G4    2048   // 4*H
#define N_WG  16     // 16 WGs x 512 threads (was 32x256): halve poll agents
#define NTHR  512
#define CHUNK 32     // h indices per workgroup
#define POLL_CAP (1 << 16)  // watchdog: finite wrong run instead of hang

#define OUT_HT 0
#define OUT_CT 512
#define OUT_Y  1024
#define OUT_A  (1024 + L_SEQ*H_DIM)   // 2098176

typedef unsigned long long ull;

__device__ __forceinline__ float fast_sigmoid(float v) {
    return 1.0f / (1.0f + __expf(-v));
}
__device__ __forceinline__ float fast_tanh(float v) {
    const float ax = fabsf(v);
    const float e = __expf(2.0f * ax);          // inf for large ax -> r = 1
    const float r = 1.0f - 2.0f / (e + 1.0f);
    return copysignf(r, v);
}

// Opaque 16B load: the asm result cannot be rematerialized, so the value MUST
// stay register-resident across the whole time loop (the compiler was sinking
// ordinary invariant loads back into the loop -> 128 KB/CU/step L2 streaming).
__device__ __forceinline__ float4 ld_f4_pin(const float* p) {
    float4 r;
    asm volatile("global_load_dwordx4 %0, %1, off\n\ts_waitcnt vmcnt(0)"
                 : "=v"(r) : "v"(p));
    return r;
}

__device__ __forceinline__ ull ld_word(ull* p) {
    return __hip_atomic_load(p, __ATOMIC_RELAXED, __HIP_MEMORY_SCOPE_AGENT);
}

// ---------------------------------------------------------------------------
// x[l, :] = embed[sent[l], :]
// ---------------------------------------------------------------------------
__global__ void gather_embed(const int* __restrict__ sent,
                             const float* __restrict__ embed,
                             float* __restrict__ x) {
    const int l = blockIdx.x;
    const int t = threadIdx.x;          // 128 threads, float4 each
    const int row = sent[l];
    const float4 v = *(const float4*)&embed[(size_t)row * H_DIM + t * 4];
    *(float4*)&x[(size_t)l * H_DIM + t * 4] = v;
}

// ---------------------------------------------------------------------------
// Generic fp32 tile GEMM (64x64 tile, BK=16, 256 thr, 4x4 micro) — unchanged.
// ---------------------------------------------------------------------------
template<bool AT, bool BT, bool ADD_C, bool BIAS>
__global__ __launch_bounds__(256) void gemm_tile(
    const float* __restrict__ A, int lda,
    const float* __restrict__ B, int ldb,
    float* __restrict__ C, int ldc,
    int K,
    const float* __restrict__ bias1,
    const float* __restrict__ bias2) {

    __shared__ float sA[16][68];
    __shared__ float sB[16][68];

    const int tid = threadIdx.x;
    const int i0 = blockIdx.y * 64;
    const int j0 = blockIdx.x * 64;
    const int ti = tid & 15;
    const int tj = tid >> 4;

    float acc[4][4] = {};

    for (int k0 = 0; k0 < K; k0 += 16) {
        if (!AT) {
            const int row = tid >> 2, kq = tid & 3;
            const float4 v = *(const float4*)&A[(size_t)(i0 + row) * lda + k0 + kq * 4];
            sA[kq * 4 + 0][row] = v.x;
            sA[kq * 4 + 1][row] = v.y;
            sA[kq * 4 + 2][row] = v.z;
            sA[kq * 4 + 3][row] = v.w;
        } else {
            const int krow = tid >> 4, ic = tid & 15;
            const float4 v = *(const float4*)&A[(size_t)(k0 + krow) * lda + i0 + ic * 4];
            *(float4*)&sA[krow][ic * 4] = v;
        }
        if (BT) {
            const int row = tid >> 2, kq = tid & 3;
            const float4 v = *(const float4*)&B[(size_t)(j0 + row) * ldb + k0 + kq * 4];
            sB[kq * 4 + 0][row] = v.x;
            sB[kq * 4 + 1][row] = v.y;
            sB[kq * 4 + 2][row] = v.z;
            sB[kq * 4 + 3][row] = v.w;
        } else {
            const int krow = tid >> 4, jc = tid & 15;
            const float4 v = *(const float4*)&B[(size_t)(k0 + krow) * ldb + j0 + jc * 4];
            *(float4*)&sB[krow][jc * 4] = v;
        }
        __syncthreads();

        #pragma unroll
        for (int kk = 0; kk < 16; ++kk) {
            const float4 a4 = *(const float4*)&sA[kk][ti * 4];
            const float4 b4 = *(const float4*)&sB[kk][tj * 4];
            const float av[4] = {a4.x, a4.y, a4.z, a4.w};
            const float bv[4] = {b4.x, b4.y, b4.z, b4.w};
            #pragma unroll
            for (int ii = 0; ii < 4; ++ii)
                #pragma unroll
                for (int jjx = 0; jjx < 4; ++jjx)
                    acc[ii][jjx] = fmaf(av[ii], bv[jjx], acc[ii][jjx]);
        }
        __syncthreads();
    }

    #pragma unroll
    for (int ii = 0; ii < 4; ++ii) {
        const size_t crow = (size_t)(i0 + ti * 4 + ii) * ldc + j0 + tj * 4;
        #pragma unroll
        for (int jjx = 0; jjx < 4; ++jjx) {
            float v = acc[ii][jjx];
            if constexpr (BIAS) {
                const int col = j0 + tj * 4 + jjx;
                v += bias1[col] + bias2[col];
            }
            if constexpr (ADD_C) v += C[crow + jjx];
            C[crow + jjx] = v;
        }
    }
}

// ---------------------------------------------------------------------------
// Row softmax of T [M_DIM x L_SEQ], in place. One block per row. Unchanged.
// ---------------------------------------------------------------------------
__global__ __launch_bounds__(256) void softmax_rows(float* __restrict__ T) {
    __shared__ float red[8];
    const int m = blockIdx.x;
    const int tid = threadIdx.x;
    float* row = T + (size_t)m * L_SEQ;

    float4 v[4];
    #pragma unroll
    for (int c = 0; c < 4; ++c)
        v[c] = *(const float4*)&row[c * 1024 + tid * 4];

    float mx = -INFINITY;
    #pragma unroll
    for (int c = 0; c < 4; ++c)
        mx = fmaxf(mx, fmaxf(fmaxf(v[c].x, v[c].y), fmaxf(v[c].z, v[c].w)));
    #pragma unroll
    for (int o = 32; o; o >>= 1) mx = fmaxf(mx, __shfl_xor(mx, o));
    if ((tid & 63) == 0) red[tid >> 6] = mx;
    __syncthreads();
    mx = fmaxf(fmaxf(red[0], red[1]), fmaxf(red[2], red[3]));

    float sum = 0.0f;
    #pragma unroll
    for (int c = 0; c < 4; ++c) {
        v[c].x = expf(v[c].x - mx);
        v[c].y = expf(v[c].y - mx);
        v[c].z = expf(v[c].z - mx);
        v[c].w = expf(v[c].w - mx);
        sum += (v[c].x + v[c].y) + (v[c].z + v[c].w);
    }
    #pragma unroll
    for (int o = 32; o; o >>= 1) sum += __shfl_xor(sum, o);
    if ((tid & 63) == 0) red[4 + (tid >> 6)] = sum;
    __syncthreads();
    sum = (red[4] + red[5]) + (red[6] + red[7]);
    const float inv = 1.0f / sum;

    #pragma unroll
    for (int c = 0; c < 4; ++c) {
        v[c].x *= inv; v[c].y *= inv; v[c].z *= inv; v[c].w *= inv;
        *(float4*)&row[c * 1024 + tid * 4] = v[c];
    }
}

__global__ void copyA(const float* __restrict__ A, float* __restrict__ dst) {
    const int idx = blockIdx.x * 256 + threadIdx.x;
    ((float4*)dst)[idx] = ((const float4*)A)[idx];
}

// ---------------------------------------------------------------------------
// Persistent multi-workgroup LSTM, fp16-pair stamped broadcast — R0 protocol
// byte-for-byte (packed hbuf, 8B stamped words, k=1 polls, store ordering),
// but decomposed as 16 WGs x 512 threads instead of 32 x 256.
//
// R8 theory: R6 (line padding -> 3x FETCH, +1ms) and R7 (4 in-flight polls,
// +2.7ms) showed step latency RISES with aggregate request pressure at the
// chip coherence point — the writer's store visibility is delayed by the
// very poll queue sampling it. So reduce the polling population: 16 WGs
// halve the agent-scope poll streams (8192 -> 4096; only tid<256 polls,
// wave-uniform — waves 4-7 skip to the barrier) and halve the number of
// discovery-maxima the step's barrier waits on. Per-thread work unchanged
// (128 FMAs, same kg/shfl microstructure); 8 waves/CU = 2/SIMD, resident.
//
// WG b owns h indices [b*32, b*32+32).
//   wave = tid>>6 (0..7); jj = wave*4 + ((lane>>4)&3); kg = lane&15.
// hbuf[t&1][256] u64 words; word j = stamp(t+1)<<32 | fp16(h[2j+1])<<16 |
// fp16(h[2j]). One relaxed agent-scope store per word (16 storing lanes/WG:
// lanes 0,32 of each wave). 2-deep overwrite-safe: the WG's pollers gate the
// barrier, so reaching t+2 requires having observed all of t+1.
// POLL_CAP watchdog (R4-proven): finite wrong run instead of a hung
// container; never fires healthy.
// ---------------------------------------------------------------------------
__global__ __launch_bounds__(NTHR, 1) void lstm_kernel(
    const float* __restrict__ Gm,     // [L_SEQ, G4] x-part + biases
    const float* __restrict__ W_hh,   // [G4, H_DIM]
    const float* __restrict__ h0,
    const float* __restrict__ c0,
    float* __restrict__ out,
    ull* hbuf) {                      // [2][256] stamped fp16-pair words

    __shared__ __align__(16) float sH[2][H_DIM];

    const int tid  = threadIdx.x;
    const int b    = blockIdx.x;
    const int lane = tid & 63;
    const int wave = tid >> 6;                // 0..7
    const int m    = (lane >> 4) & 3;
    const int jj   = wave * 4 + m;            // 0..31
    const int kg   = lane & 15;
    const int gj   = b * CHUNK + jj;          // global h index this thread serves

    // --- weights, rotated by kg, PINNED in VGPRs via opaque asm loads
    float4 w[4][8];
    #pragma unroll
    for (int g = 0; g < 4; ++g) {
        const float* wrow = W_hh + (size_t)(g * H_DIM + gj) * H_DIM + kg * 32;
        #pragma unroll
        for (int i = 0; i < 8; ++i)
            w[g][i] = ld_f4_pin(&wrow[((i + kg) & 7) * 4]);
    }

    // --- init h, c (512 threads, one float each)
    sH[0][tid] = h0[tid];
    float c = 0.0f;
    if (kg == 0) c = c0[gj];
    __syncthreads();

    // --- prefetch gate inputs for t=0
    float gin0 = 0.f, gin1 = 0.f, gin2 = 0.f, gin3 = 0.f;
    if (kg == 0) {
        const float* gp = Gm + gj;
        gin0 = gp[0 * H_DIM];
        gin1 = gp[1 * H_DIM];
        gin2 = gp[2 * H_DIM];
        gin3 = gp[3 * H_DIM];
    }

    bool dead = false;   // sticky watchdog flag — never set in a healthy run

    for (int t = 0; t < L_SEQ; ++t) {
        const float4* sH4 = (const float4*)sH[t & 1];

        // prefetch gate inputs for t+1 (latency hides under this whole step)
        float nin0 = 0.f, nin1 = 0.f, nin2 = 0.f, nin3 = 0.f;
        if (kg == 0 && t + 1 < L_SEQ) {
            const float* gp = Gm + (size_t)(t + 1) * G4 + gj;
            nin0 = gp[0 * H_DIM];
            nin1 = gp[1 * H_DIM];
            nin2 = gp[2 * H_DIM];
            nin3 = gp[3 * H_DIM];
        }

        // partial dots: 4 gates x 32 k-floats
        float4 a0 = {0, 0, 0, 0}, a1 = {0, 0, 0, 0}, a2 = {0, 0, 0, 0}, a3 = {0, 0, 0, 0};
        #pragma unroll
        for (int i = 0; i < 8; ++i) {
            const float4 hv = sH4[kg * 8 + ((i + kg) & 7)];
            a0.x = fmaf(w[0][i].x, hv.x, a0.x); a0.y = fmaf(w[0][i].y, hv.y, a0.y);
            a0.z = fmaf(w[0][i].z, hv.z, a0.z); a0.w = fmaf(w[0][i].w, hv.w, a0.w);
            a1.x = fmaf(w[1][i].x, hv.x, a1.x); a1.y = fmaf(w[1][i].y, hv.y, a1.y);
            a1.z = fmaf(w[1][i].z, hv.z, a1.z); a1.w = fmaf(w[1][i].w, hv.w, a1.w);
            a2.x = fmaf(w[2][i].x, hv.x, a2.x); a2.y = fmaf(w[2][i].y, hv.y, a2.y);
            a2.z = fmaf(w[2][i].z, hv.z, a2.z); a2.w = fmaf(w[2][i].w, hv.w, a2.w);
            a3.x = fmaf(w[3][i].x, hv.x, a3.x); a3.y = fmaf(w[3][i].y, hv.y, a3.y);
            a3.z = fmaf(w[3][i].z, hv.z, a3.z); a3.w = fmaf(w[3][i].w, hv.w, a3.w);
        }
        float s0 = (a0.x + a0.y) + (a0.z + a0.w);
        float s1 = (a1.x + a1.y) + (a1.z + a1.w);
        float s2 = (a2.x + a2.y) + (a2.z + a2.w);
        float s3 = (a3.x + a3.y) + (a3.z + a3.w);
        #pragma unroll
        for (int msk = 1; msk <= 8; msk <<= 1) {
            s0 += __shfl_xor(s0, msk);
            s1 += __shfl_xor(s1, msk);
            s2 += __shfl_xor(s2, msk);
            s3 += __shfl_xor(s3, msk);
        }

        if (kg == 0) {
            const float i_ = fast_sigmoid(s0 + gin0);
            const float f_ = fast_sigmoid(s1 + gin1);
            const float g_ = fast_tanh(s2 + gin2);
            const float o_ = fast_sigmoid(s3 + gin3);
            c = f_ * c + i_ * g_;
            const float h = o_ * fast_tanh(c);
            // pair up: even-jj lane gets odd-jj partner's h (lane 0<-16, 32<-48)
            const float hp = __shfl_xor(h, 16);
            if ((m & 1) == 0) {
                const __half2 p2 = __floats2half2_rn(h, hp);   // lo = even jj
                const unsigned bits = __builtin_bit_cast(unsigned, p2);
                const ull pack = ((ull)(unsigned)(t + 1) << 32) | (ull)bits;
                __hip_atomic_store(&hbuf[(t & 1) * 256 + (gj >> 1)], pack,
                                   __ATOMIC_RELAXED, __HIP_MEMORY_SCOPE_AGENT);
            }
            out[OUT_Y + (size_t)t * H_DIM + gj] = h;
            if (t == L_SEQ - 1) {
                out[OUT_HT + gj] = h;
                out[OUT_CT + gj] = c;
                out[OUT_A + (size_t)M_DIM * H_DIM + gj] = h;   // A_new last row
            }
        }
        gin0 = nin0; gin1 = nin1; gin2 = nin2; gin3 = nin3;

        if (t + 1 < L_SEQ && tid < 256) {
            // wave-uniform split: waves 0-3 poll one word each (k=1, the
            // proven R0 sampling); waves 4-7 go straight to the barrier.
            const unsigned want = (unsigned)(t + 1);
            ull* src = &hbuf[(t & 1) * 256 + tid];
            ull v;
            int guard = 0;
            do {
                v = ld_word(src);
                if ((unsigned)(v >> 32) == want) break;
                if (dead) break;
                if (++guard > POLL_CAP) { dead = true; break; }
            } while (true);
            const __half2 p2 = __builtin_bit_cast(__half2, (unsigned)v);
            const float2 f2 = __half22float2(p2);
            float* dstp = sH[(t + 1) & 1];
            dstp[tid * 2]     = f2.x;
            dstp[tid * 2 + 1] = f2.y;
        }
        __syncthreads();
    }
}

// ---------------------------------------------------------------------------
extern "C" void kernel_launch(void* const* d_in, const int* in_sizes, int n_in,
                              void* d_out, int out_size, void* d_ws, size_t ws_size,
                              hipStream_t stream) {
    const int*   sent  = (const int*)d_in[0];
    const float* h0    = (const float*)d_in[1];
    const float* c0    = (const float*)d_in[2];
    const float* A     = (const float*)d_in[3];
    const float* embed = (const float*)d_in[4];
    const float* W_ih  = (const float*)d_in[5];
    const float* W_hh  = (const float*)d_in[6];
    const float* b_ih  = (const float*)d_in[7];
    const float* b_hh  = (const float*)d_in[8];
    float* out = (float*)d_out;

    float* ws = (float*)d_ws;
    float* x    = ws;                                  // L*H       (8 MB)
    float* T    = x + (size_t)L_SEQ * H_DIM;           // M*L       (16 MB)
    float* Gm   = T + (size_t)M_DIM * L_SEQ;           // L*4H      (32 MB)
    ull*   hbuf = (ull*)(Gm + (size_t)L_SEQ * G4);     // 2*256 u64 (R0 layout)
    // 0xAA poison in hbuf: stamp 0xAAAAAAAA never equals a wanted stamp.

    // x = embed[sent]
    gather_embed<<<L_SEQ, 128, 0, stream>>>(sent, embed, x);

    // T = A @ x^T   [M, L], K = H
    gemm_tile<false, true, false, false><<<dim3(L_SEQ / 64, M_DIM / 64), 256, 0, stream>>>(
        A, H_DIM, x, H_DIM, T, L_SEQ, H_DIM, nullptr, nullptr);

    // row softmax over L
    softmax_rows<<<M_DIM, 256, 0, stream>>>(T);

    // x += T^T @ A   [L, H], K = M
    gemm_tile<true, false, true, false><<<dim3(H_DIM / 64, L_SEQ / 64), 256, 0, stream>>>(
        T, L_SEQ, A, H_DIM, x, H_DIM, M_DIM, nullptr, nullptr);

    // G = x @ W_ih^T + b_ih + b_hh   [L, 4H], K = H
    gemm_tile<false, true, false, true><<<dim3(G4 / 64, L_SEQ / 64), 256, 0, stream>>>(
        x, H_DIM, W_ih, H_DIM, Gm, G4, H_DIM, b_ih, b_hh);

    // A_new rows 0..M-1
    copyA<<<(M_DIM * H_DIM / 4) / 256, 256, 0, stream>>>(A, out + OUT_A);

    // sequential LSTM over L steps (fp16-pair stamped broadcast, pinned weights)
    lstm_kernel<<<N_WG, NTHR, 0, stream>>>(Gm, W_hh, h0, c0, out, hbuf);
}